// Round 1
// baseline (123.363 us; speedup 1.0000x reference)
//
#include <hip/hip_runtime.h>
#include <hip/hip_bf16.h>

typedef __attribute__((ext_vector_type(4))) float f32x4;
typedef __attribute__((ext_vector_type(8))) short s16x8;
typedef __attribute__((ext_vector_type(4))) short s16x4;

#define MFMA16(a, b, c) __builtin_amdgcn_mfma_f32_16x16x32_bf16(a, b, c, 0, 0, 0)

// elements per Q/K/V plane: 32 n * 12544 u * 32 d
#define PLANE ((size_t)12845056)

__device__ __forceinline__ unsigned short f2bf(float f) {
  union { float f; unsigned u; } v; v.f = f;
  unsigned u = v.u;
  u += 0x7fff + ((u >> 16) & 1);   // RNE
  return (unsigned short)(u >> 16);
}

// ---------------------------------------------------------------------------
// GEMM1: qkv = x @ qkv_w.T + qkv_b, rolled(-4) rows, output scattered into
// window-layout planes ws[s][n][u][d] (bf16). Columns permuted: col' = s*128+c2
// maps to original j = c2*3 + s  (reference reshape (...,C,3)).
// ---------------------------------------------------------------------------
__global__ __launch_bounds__(256, 2)
void k_gemm_qkv(const float* __restrict__ X, const float* __restrict__ W,
                const float* __restrict__ B, unsigned short* __restrict__ OUT) {
  __shared__ unsigned short Alds[128 * 128];
  __shared__ unsigned short Blds[128 * 128];
  const int tid = threadIdx.x;
  const int bm = blockIdx.x;
  const int s = blockIdx.y;

  {
    const int rbase = tid >> 5;   // 0..7
    const int ck = tid & 31;      // f32x4 chunk within 128-float row
    for (int pass = 0; pass < 16; ++pass) {
      const int rr = pass * 8 + rbase;
      const int row = bm * 128 + rr;          // n*3136 + p_rolled
      const int n = row / 3136;
      const int p = row - n * 3136;
      const int r_ = p / 56;
      const int c_ = p - r_ * 56;
      int ro = r_ + 4; if (ro >= 56) ro -= 56;   // roll(-4): rolled[r'] = orig[(r'+4)%56]
      int co = c_ + 4; if (co >= 56) co -= 56;
      const f32x4 v = *(const f32x4*)(X + (((size_t)n * 3136 + ro * 56 + co) << 7) + (ck << 2));
      s16x4 h;
      h.x = (short)f2bf(v.x); h.y = (short)f2bf(v.y);
      h.z = (short)f2bf(v.z); h.w = (short)f2bf(v.w);
      const int byte = (ck << 3) ^ ((rr & 7) << 4);     // XOR swizzle, 16B granules
      *(s16x4*)((char*)Alds + rr * 256 + byte) = h;
    }
    for (int pass = 0; pass < 16; ++pass) {
      const int rr = pass * 8 + rbase;        // c2 (permuted col)
      const int j = rr * 3 + s;               // original weight row
      const f32x4 v = *(const f32x4*)(W + (size_t)j * 128 + (ck << 2));
      s16x4 h;
      h.x = (short)f2bf(v.x); h.y = (short)f2bf(v.y);
      h.z = (short)f2bf(v.z); h.w = (short)f2bf(v.w);
      const int byte = (ck << 3) ^ ((rr & 7) << 4);
      *(s16x4*)((char*)Blds + rr * 256 + byte) = h;
    }
  }
  __syncthreads();

  const int lane = tid & 63;
  const int wid = tid >> 6;
  const int li = lane & 15;
  const int hi = lane >> 4;
  const int rw = (wid >> 1) << 6;
  const int cw = (wid & 1) << 6;

  f32x4 acc[4][4];
#pragma unroll
  for (int i = 0; i < 4; ++i)
#pragma unroll
    for (int j = 0; j < 4; ++j) acc[i][j] = (f32x4){0.f, 0.f, 0.f, 0.f};

#pragma unroll
  for (int kc = 0; kc < 4; ++kc) {
    s16x8 af[4], bfr[4];
#pragma unroll
    for (int i = 0; i < 4; ++i) {
      const int ra = rw + i * 16 + li;
      af[i] = *(const s16x8*)((const char*)Alds + ra * 256 + ((kc * 64 + hi * 16) ^ ((ra & 7) << 4)));
      const int cb = cw + i * 16 + li;
      bfr[i] = *(const s16x8*)((const char*)Blds + cb * 256 + ((kc * 64 + hi * 16) ^ ((cb & 7) << 4)));
    }
#pragma unroll
    for (int i = 0; i < 4; ++i)
#pragma unroll
      for (int j = 0; j < 4; ++j)
        acc[i][j] = MFMA16(af[i], bfr[j], acc[i][j]);
  }

  // epilogue: scatter into window-layout plane s
  float bias4[4];
  int cgd4[4];
#pragma unroll
  for (int j = 0; j < 4; ++j) {
    const int c2 = cw + j * 16 + li;
    bias4[j] = B[c2 * 3 + s];
    cgd4[j] = ((c2 >> 5) << 5) + (c2 & 31);   // = c2, but kept explicit: u-offset (cg)*32 + d
  }
  unsigned short* outS = OUT + (size_t)s * PLANE;
#pragma unroll
  for (int i = 0; i < 4; ++i) {
#pragma unroll
    for (int r = 0; r < 4; ++r) {
      const int row = bm * 128 + rw + i * 16 + hi * 4 + r;
      const int n = row / 3136;
      const int p = row - n * 3136;           // p_rolled
      const size_t base = ((size_t)(n * 12544 + p * 4) << 5);   // u = p*4 + cg
#pragma unroll
      for (int j = 0; j < 4; ++j)
        outS[base + cgd4[j]] = f2bf(acc[i][j][r] + bias4[j]);
    }
  }
}

// ---------------------------------------------------------------------------
// Attention: one wave per (n, m, wh, ww) group. 49 tokens x 32 dims, padded to 64.
// ---------------------------------------------------------------------------
__global__ __launch_bounds__(64, 3)
void k_attn(const unsigned short* __restrict__ QKV, const float* __restrict__ RPE,
            unsigned short* __restrict__ AOUT) {
  __shared__ unsigned short Vt[32][72];   // V transposed [d][t], t>=49 zeroed
  __shared__ unsigned short P[64][72];    // unnormalized softmax weights (bf16)
  __shared__ float rpe[169];

  const int lane = threadIdx.x;
  const int blk = blockIdx.x;
  const int n = blk >> 8;
  const int rem = blk & 255;              // m*64 + wh*8 + ww ; u_base = rem*49
  const int wh = (rem >> 3) & 7;
  const int ww = rem & 7;
  const size_t rowbase = ((size_t)n * 12544 + rem * 49) << 5;
  const unsigned short* qp = QKV + rowbase;
  const unsigned short* kp = qp + PLANE;
  const unsigned short* vp = kp + PLANE;

  for (int i = lane; i < 169; i += 64) rpe[i] = RPE[i];

  {
    const int t = lane;
    const unsigned short* vrow = vp + t * 32;
#pragma unroll
    for (int dp = 0; dp < 16; ++dp) {
      unsigned v = 0;
      if (t < 49) v = *(const unsigned*)(vrow + dp * 2);
      Vt[dp * 2][t] = (unsigned short)(v & 0xffffu);
      Vt[dp * 2 + 1][t] = (unsigned short)(v >> 16);
    }
  }

  const int li = lane & 15;
  const int hi = lane >> 4;

  // Q/K fragments straight from global (rows are contiguous in window layout).
  s16x8 qf[4], kf[4];
#pragma unroll
  for (int i = 0; i < 4; ++i) {
    qf[i] = *(const s16x8*)(qp + (i * 16 + li) * 32 + hi * 8);
    kf[i] = *(const s16x8*)(kp + (i * 16 + li) * 32 + hi * 8);
  }

  const f32x4 zf = (f32x4){0.f, 0.f, 0.f, 0.f};
  f32x4 sc[4][4];
#pragma unroll
  for (int i = 0; i < 4; ++i)
#pragma unroll
    for (int j = 0; j < 4; ++j)
      sc[i][j] = MFMA16(qf[i], kf[j], zf);   // D[q][k] = sum_d Q[q][d]K[k][d]

  int xk[4], yk[4];
#pragma unroll
  for (int j = 0; j < 4; ++j) {
    const int k = j * 16 + li;
    xk[j] = k / 7;
    yk[j] = k - xk[j] * 7;
  }
  const bool rmask = (wh == 7);
  const bool cmask = (ww == 7);

  __syncthreads();   // rpe + Vt visible

  float rinv[4][4];
#pragma unroll
  for (int i = 0; i < 4; ++i) {
#pragma unroll
    for (int r = 0; r < 4; ++r) {
      const int q = i * 16 + hi * 4 + r;
      const int xq = q / 7;
      const int yq = q - xq * 7;
      float lv[4];
      float mx = -3.0e38f;
#pragma unroll
      for (int j = 0; j < 4; ++j) {
        const int k = j * 16 + li;
        float L = -1.0e30f;
        if (q < 49 && k < 49) {
          L = sc[i][j][r] * 0.17677669529663687f + rpe[(xk[j] - xq + 6) * 13 + (yk[j] - yq + 6)];
          if (rmask && ((xq >= 4) != (xk[j] >= 4))) L = -1.0e30f;
          if (cmask && (((yq == 4) && (yk[j] < 4)) || ((yq < 4) && (yk[j] >= 4)))) L = -1.0e30f;
        }
        lv[j] = L;
        mx = fmaxf(mx, L);
      }
#pragma unroll
      for (int d = 1; d < 16; d <<= 1) mx = fmaxf(mx, __shfl_xor(mx, d));
      float sum = 0.f;
#pragma unroll
      for (int j = 0; j < 4; ++j) {
        const float p = __expf(lv[j] - mx);
        lv[j] = p;
        sum += p;
      }
#pragma unroll
      for (int d = 1; d < 16; d <<= 1) sum += __shfl_xor(sum, d);
      rinv[i][r] = 1.0f / sum;
#pragma unroll
      for (int j = 0; j < 4; ++j) P[q][j * 16 + li] = f2bf(lv[j]);
    }
  }
  __syncthreads();

  s16x8 vf[2][2];
#pragma unroll
  for (int kc = 0; kc < 2; ++kc)
#pragma unroll
    for (int fn = 0; fn < 2; ++fn)
      vf[kc][fn] = *(const s16x8*)&Vt[fn * 16 + li][kc * 32 + hi * 8];

  f32x4 o[4][2];
#pragma unroll
  for (int i = 0; i < 4; ++i) { o[i][0] = zf; o[i][1] = zf; }
#pragma unroll
  for (int i = 0; i < 4; ++i) {
#pragma unroll
    for (int kc = 0; kc < 2; ++kc) {
      const s16x8 pf = *(const s16x8*)&P[i * 16 + li][kc * 32 + hi * 8];
      o[i][0] = MFMA16(pf, vf[kc][0], o[i][0]);
      o[i][1] = MFMA16(pf, vf[kc][1], o[i][1]);
    }
  }

  unsigned short* obase = AOUT + rowbase;
#pragma unroll
  for (int i = 0; i < 4; ++i) {
#pragma unroll
    for (int r = 0; r < 4; ++r) {
      const int q = i * 16 + hi * 4 + r;
      if (q < 49) {
        const float ri = rinv[i][r];
        obase[q * 32 + li] = f2bf(o[i][0][r] * ri);
        obase[q * 32 + 16 + li] = f2bf(o[i][1][r] * ri);
      }
    }
  }
}

// ---------------------------------------------------------------------------
// GEMM3: out = attn @ out_w.T + out_b, gathering rolled(+3) rows from window
// layout (rows are 256B contiguous), fp32 output.
// ---------------------------------------------------------------------------
__global__ __launch_bounds__(256, 2)
void k_gemm_out(const unsigned short* __restrict__ A, const float* __restrict__ W,
                const float* __restrict__ B, float* __restrict__ OUT) {
  __shared__ unsigned short Alds[128 * 128];
  __shared__ unsigned short Blds[128 * 128];
  const int tid = threadIdx.x;
  const int bm = blockIdx.x;

  {
    const int rbase = tid >> 4;   // 0..15
    const int ck = tid & 15;      // 16B chunk
    for (int pass = 0; pass < 8; ++pass) {
      const int rr = pass * 16 + rbase;
      const int row = bm * 128 + rr;          // n*3136 + p_final
      const int n = row / 3136;
      const int p = row - n * 3136;
      const int rf = p / 56, cf = p - rf * 56;
      int rs = rf + 53; if (rs >= 56) rs -= 56;   // roll(+3): final[r] = attn[(r-3)%56]
      int cs = cf + 53; if (cs >= 56) cs -= 56;
      const s16x8 v = *(const s16x8*)(A + (((size_t)n * 12544 + (rs * 56 + cs) * 4) << 5) + (ck << 3));
      const int byte = (ck << 4) ^ ((rr & 7) << 4);
      *(s16x8*)((char*)Alds + rr * 256 + byte) = v;
    }
    const int rb2 = tid >> 5;
    const int ck2 = tid & 31;
    for (int pass = 0; pass < 16; ++pass) {
      const int rr = pass * 8 + rb2;
      const f32x4 v = *(const f32x4*)(W + (size_t)rr * 128 + (ck2 << 2));
      s16x4 h;
      h.x = (short)f2bf(v.x); h.y = (short)f2bf(v.y);
      h.z = (short)f2bf(v.z); h.w = (short)f2bf(v.w);
      const int byte = (ck2 << 3) ^ ((rr & 7) << 4);
      *(s16x4*)((char*)Blds + rr * 256 + byte) = h;
    }
  }
  __syncthreads();

  const int lane = tid & 63;
  const int wid = tid >> 6;
  const int li = lane & 15;
  const int hi = lane >> 4;
  const int rw = (wid >> 1) << 6;
  const int cw = (wid & 1) << 6;

  f32x4 acc[4][4];
#pragma unroll
  for (int i = 0; i < 4; ++i)
#pragma unroll
    for (int j = 0; j < 4; ++j) acc[i][j] = (f32x4){0.f, 0.f, 0.f, 0.f};

#pragma unroll
  for (int kc = 0; kc < 4; ++kc) {
    s16x8 af[4], bfr[4];
#pragma unroll
    for (int i = 0; i < 4; ++i) {
      const int ra = rw + i * 16 + li;
      af[i] = *(const s16x8*)((const char*)Alds + ra * 256 + ((kc * 64 + hi * 16) ^ ((ra & 7) << 4)));
      const int cb = cw + i * 16 + li;
      bfr[i] = *(const s16x8*)((const char*)Blds + cb * 256 + ((kc * 64 + hi * 16) ^ ((cb & 7) << 4)));
    }
#pragma unroll
    for (int i = 0; i < 4; ++i)
#pragma unroll
      for (int j = 0; j < 4; ++j)
        acc[i][j] = MFMA16(af[i], bfr[j], acc[i][j]);
  }

  float bias4[4];
#pragma unroll
  for (int j = 0; j < 4; ++j) bias4[j] = B[cw + j * 16 + li];
#pragma unroll
  for (int i = 0; i < 4; ++i) {
#pragma unroll
    for (int r = 0; r < 4; ++r) {
      const int row = bm * 128 + rw + i * 16 + hi * 4 + r;
      float* orow = OUT + (size_t)row * 128;
#pragma unroll
      for (int j = 0; j < 4; ++j)
        orow[cw + j * 16 + li] = acc[i][j][r] + bias4[j];
    }
  }
}

extern "C" void kernel_launch(void* const* d_in, const int* in_sizes, int n_in,
                              void* d_out, int out_size, void* d_ws, size_t ws_size,
                              hipStream_t stream) {
  const float* x = (const float*)d_in[0];
  const float* qkv_w = (const float*)d_in[1];
  const float* qkv_b = (const float*)d_in[2];
  const float* out_w = (const float*)d_in[3];
  const float* out_b = (const float*)d_in[4];
  const float* rpe = (const float*)d_in[5];
  float* out = (float*)d_out;

  unsigned short* qkv_ws = (unsigned short*)d_ws;          // 3 planes
  unsigned short* aout = qkv_ws + 3 * PLANE;               // 1 plane

  k_gemm_qkv<<<dim3(784, 3), 256, 0, stream>>>(x, qkv_w, qkv_b, qkv_ws);
  k_attn<<<8192, 64, 0, stream>>>(qkv_ws, rpe, aout);
  k_gemm_out<<<784, 256, 0, stream>>>(aout, out_w, out_b, out);
}

// Round 2
// 83.947 us; speedup vs baseline: 1.4695x; 1.4695x over previous
//
#include <hip/hip_runtime.h>
#include <hip/hip_bf16.h>

typedef __attribute__((ext_vector_type(4))) float f32x4;
typedef __attribute__((ext_vector_type(8))) short s16x8;
typedef __attribute__((ext_vector_type(4))) short s16x4;

#define MFMA16(a, b, c) __builtin_amdgcn_mfma_f32_16x16x32_bf16(a, b, c, 0, 0, 0)

// elements per Q/K/V plane: 32 n * 12544 u * 32 d
#define PLANE ((size_t)12845056)

__device__ __forceinline__ unsigned short f2bf(float f) {
  union { float f; unsigned u; } v; v.f = f;
  unsigned u = v.u;
  u += 0x7fff + ((u >> 16) & 1);   // RNE
  return (unsigned short)(u >> 16);
}
__device__ __forceinline__ float bf2f(unsigned short h) {
  union { unsigned u; float f; } v; v.u = ((unsigned)h) << 16;
  return v.f;
}

typedef const __attribute__((address_space(1))) char gas_char;
typedef __attribute__((address_space(3))) char las_char;
__device__ __forceinline__ void gload_lds16(const void* g, void* l) {
  __builtin_amdgcn_global_load_lds((gas_char*)g, (las_char*)l, 16, 0, 0);
}

// ---------------------------------------------------------------------------
// Prepass: convert qkv_w -> W2[s][c2][k] bf16 (rows pre-swizzled), out_w -> W3,
// and bake bias+mask tables BIAS[4][64][64].
// ---------------------------------------------------------------------------
__global__ void k_prep(const float* __restrict__ QW, const float* __restrict__ OW,
                       const float* __restrict__ RPE,
                       unsigned short* __restrict__ W2, unsigned short* __restrict__ W3,
                       float* __restrict__ BIAS) {
  const int b = blockIdx.x, t = threadIdx.x;
  if (b < 24) {                       // qkv_w: 3*128*128 elems, 8 per thread
    const int e = (b * 256 + t) * 8;
    const int s = e >> 14;
    const int r = e & 16383;
    const int c2 = r >> 7;
    const int k0 = r & 127;
    const float* src = QW + (size_t)(c2 * 3 + s) * 128 + k0;
    s16x8 h;
#pragma unroll
    for (int q = 0; q < 8; ++q) ((short*)&h)[q] = (short)f2bf(src[q]);
    *(s16x8*)((char*)(W2 + (size_t)s * 16384 + c2 * 128) + ((k0 * 2) ^ ((c2 & 7) << 4))) = h;
  } else if (b < 32) {                // out_w: 128*128
    const int e = ((b - 24) * 256 + t) * 8;
    const int c = e >> 7;
    const int k0 = e & 127;
    const float* src = OW + (size_t)c * 128 + k0;
    s16x8 h;
#pragma unroll
    for (int q = 0; q < 8; ++q) ((short*)&h)[q] = (short)f2bf(src[q]);
    *(s16x8*)((char*)(W3 + c * 128) + ((k0 * 2) ^ ((c & 7) << 4))) = h;
  } else {                            // bias tables, 4 classes
    const int cl = b - 32;
    const int rm = cl >> 1, cm = cl & 1;
    for (int i = 0; i < 16; ++i) {
      const int entry = i * 256 + t;
      const int q = entry >> 6, k = entry & 63;
      float v;
      if (q >= 49 || k >= 49) v = -1.0e30f;
      else {
        const int xq = q / 7, yq = q - xq * 7;
        const int xk = k / 7, yk = k - xk * 7;
        v = RPE[(xk - xq + 6) * 13 + (yk - yq + 6)];
        if (rm && ((xq >= 4) != (xk >= 4))) v = -1.0e30f;
        if (cm && (((yq == 4) && (yk < 4)) || ((yq < 4) && (yk >= 4)))) v = -1.0e30f;
      }
      BIAS[cl * 4096 + entry] = v;
    }
  }
}

// ---------------------------------------------------------------------------
// GEMM1: qkv = x @ qkv_w.T + qkv_b, rolled(-4), all 3 s per block (A staged
// once, A-frags cached in VGPR), B via global_load_lds from pre-swizzled W2.
// ---------------------------------------------------------------------------
__global__ __launch_bounds__(256, 2)
void k_gemm_qkv(const float* __restrict__ X, const unsigned short* __restrict__ W2,
                const float* __restrict__ B, unsigned short* __restrict__ OUT) {
  __shared__ unsigned short Alds[128 * 128];
  __shared__ unsigned short Blds[128 * 128];
  const int tid = threadIdx.x;
  const int bm = blockIdx.x;
  const int lane = tid & 63, wid = tid >> 6;

  // issue B(s=0) async while we stage+convert A
  {
    const char* gb = (const char*)W2 + (wid << 13) + (lane << 4);
    char* lb = (char*)Blds + (wid << 13);
#pragma unroll
    for (int r = 0; r < 8; ++r) gload_lds16(gb + (r << 10), lb + (r << 10));
  }

  // stage A: 2 threads per row, convert fp32 -> bf16, XOR-swizzled rows
  {
    const int rr = tid >> 1;
    const int row = bm * 128 + rr;
    const int n = row / 3136;
    const int p = row - n * 3136;
    const int r_ = p / 56, c_ = p - r_ * 56;
    int ro = r_ + 4; if (ro >= 56) ro -= 56;   // roll(-4)
    int co = c_ + 4; if (co >= 56) co -= 56;
    const float* src = X + (((size_t)n * 3136 + ro * 56 + co) << 7);
    char* arow = (char*)Alds + rr * 256;
#pragma unroll
    for (int gi = 0; gi < 8; ++gi) {
      const int g = ((tid & 1) << 3) + gi;
      const f32x4 v0 = *(const f32x4*)(src + g * 8);
      const f32x4 v1 = *(const f32x4*)(src + g * 8 + 4);
      s16x8 h;
      h[0] = (short)f2bf(v0.x); h[1] = (short)f2bf(v0.y);
      h[2] = (short)f2bf(v0.z); h[3] = (short)f2bf(v0.w);
      h[4] = (short)f2bf(v1.x); h[5] = (short)f2bf(v1.y);
      h[6] = (short)f2bf(v1.z); h[7] = (short)f2bf(v1.w);
      *(s16x8*)(arow + ((g << 4) ^ ((rr & 7) << 4))) = h;
    }
  }
  __syncthreads();   // drains vmcnt (B0 landed) + A visible

  const int li = lane & 15, hi = lane >> 4;
  const int rw = (wid >> 1) << 6, cw = (wid & 1) << 6;

  // epilogue row bases (shared across the 3 s-passes)
  unsigned ebase[4][4];
#pragma unroll
  for (int i = 0; i < 4; ++i)
#pragma unroll
    for (int r = 0; r < 4; ++r) {
      const int row = bm * 128 + rw + i * 16 + hi * 4 + r;
      const int n = row / 3136;
      const int p = row - n * 3136;
      ebase[i][r] = (unsigned)((n * 12544 + p * 4) << 5);
    }

  // A fragments cached across all 3 s-passes
  s16x8 af[4][4];   // [kc][i]
#pragma unroll
  for (int kc = 0; kc < 4; ++kc)
#pragma unroll
    for (int i = 0; i < 4; ++i) {
      const int ra = rw + i * 16 + li;
      af[kc][i] = *(const s16x8*)((const char*)Alds + ra * 256 + ((kc * 64 + hi * 16) ^ ((ra & 7) << 4)));
    }

  for (int s = 0; s < 3; ++s) {
    f32x4 acc[4][4];
#pragma unroll
    for (int i = 0; i < 4; ++i)
#pragma unroll
      for (int j = 0; j < 4; ++j) acc[i][j] = (f32x4){0.f, 0.f, 0.f, 0.f};

#pragma unroll
    for (int kc = 0; kc < 4; ++kc) {
      s16x8 bfr[4];
#pragma unroll
      for (int j = 0; j < 4; ++j) {
        const int cb = cw + j * 16 + li;
        bfr[j] = *(const s16x8*)((const char*)Blds + cb * 256 + ((kc * 64 + hi * 16) ^ ((cb & 7) << 4)));
      }
#pragma unroll
      for (int i = 0; i < 4; ++i)
#pragma unroll
        for (int j = 0; j < 4; ++j)
          acc[i][j] = MFMA16(af[kc][i], bfr[j], acc[i][j]);
    }

    __syncthreads();                 // everyone done reading Blds(s)
    if (s < 2) {                     // prefetch B(s+1) under the epilogue
      const char* gb = (const char*)W2 + (size_t)(s + 1) * 32768 + (wid << 13) + (lane << 4);
      char* lb = (char*)Blds + (wid << 13);
#pragma unroll
      for (int r = 0; r < 8; ++r) gload_lds16(gb + (r << 10), lb + (r << 10));
    }

    float bias4[4];
#pragma unroll
    for (int j = 0; j < 4; ++j) bias4[j] = B[(cw + j * 16 + li) * 3 + s];
    unsigned short* outS = OUT + (size_t)s * PLANE;
#pragma unroll
    for (int i = 0; i < 4; ++i)
#pragma unroll
      for (int r = 0; r < 4; ++r)
#pragma unroll
        for (int j = 0; j < 4; ++j)
          outS[ebase[i][r] + cw + j * 16 + li] = f2bf(acc[i][j][r] + bias4[j]);

    if (s < 2) __syncthreads();      // B(s+1) landed (vmcnt drained here)
  }
}

// ---------------------------------------------------------------------------
// Attention: one wave per window group; bias from precomputed table; no
// max-subtraction; V fragments direct from global; only P goes through LDS.
// ---------------------------------------------------------------------------
__global__ __launch_bounds__(64, 3)
void k_attn(const unsigned short* __restrict__ QKV, const float* __restrict__ BIAS,
            unsigned short* __restrict__ AOUT) {
  __shared__ unsigned short P[64][72];

  const int lane = threadIdx.x;
  const int blk = blockIdx.x;
  const int n = blk >> 8;
  const int rem = blk & 255;              // m*64 + wh*8 + ww
  const int wh = (rem >> 3) & 7;
  const int ww = rem & 7;
  const size_t rowbase = ((size_t)(n * 12544 + rem * 49)) << 5;
  const unsigned short* qp = QKV + rowbase;
  const unsigned short* kp = qp + PLANE;
  const unsigned short* vp = kp + PLANE;
  const float* bias = BIAS + ((wh == 7 ? 2 : 0) + (ww == 7 ? 1 : 0)) * 4096;

  const int li = lane & 15, hi = lane >> 4;

  s16x8 qf[4], kf[4];
#pragma unroll
  for (int i = 0; i < 4; ++i) {
    qf[i] = *(const s16x8*)(qp + (i * 16 + li) * 32 + hi * 8);
    kf[i] = *(const s16x8*)(kp + (i * 16 + li) * 32 + hi * 8);
  }

  const f32x4 zf = (f32x4){0.f, 0.f, 0.f, 0.f};
  f32x4 sc[4][4];
#pragma unroll
  for (int i = 0; i < 4; ++i)
#pragma unroll
    for (int j = 0; j < 4; ++j)
      sc[i][j] = MFMA16(qf[i], kf[j], zf);   // D[q][k]

  float rinv[4][4];
#pragma unroll
  for (int i = 0; i < 4; ++i) {
#pragma unroll
    for (int r = 0; r < 4; ++r) {
      const int q = i * 16 + hi * 4 + r;
      const float* brow = bias + q * 64 + li;
      float sum = 0.f;
      unsigned short pb[4];
#pragma unroll
      for (int j = 0; j < 4; ++j) {
        const float L = fmaf(sc[i][j][r], 0.17677669529663687f, brow[j * 16]);
        const unsigned short b = f2bf(__expf(L));
        pb[j] = b;
        sum += bf2f(b);
      }
#pragma unroll
      for (int d = 1; d < 16; d <<= 1) sum += __shfl_xor(sum, d);
      rinv[i][r] = 1.0f / sum;
#pragma unroll
      for (int j = 0; j < 4; ++j) P[q][j * 16 + li] = pb[j];
    }
  }

  // V B-fragments direct from global (L2-hot); issued before the barrier so
  // the barrier's vmcnt drain covers them.
  s16x8 vf[2][2];
#pragma unroll
  for (int kc = 0; kc < 2; ++kc)
#pragma unroll
    for (int fn = 0; fn < 2; ++fn) {
      s16x8 t;
#pragma unroll
      for (int j = 0; j < 8; ++j)
        ((short*)&t)[j] = *(const short*)(vp + (kc * 32 + hi * 8 + j) * 32 + fn * 16 + li);
      vf[kc][fn] = t;
    }

  __syncthreads();

  f32x4 o[4][2];
#pragma unroll
  for (int i = 0; i < 4; ++i) { o[i][0] = zf; o[i][1] = zf; }
#pragma unroll
  for (int i = 0; i < 4; ++i) {
#pragma unroll
    for (int kc = 0; kc < 2; ++kc) {
      const s16x8 pf = *(const s16x8*)&P[i * 16 + li][kc * 32 + hi * 8];
      o[i][0] = MFMA16(pf, vf[kc][0], o[i][0]);
      o[i][1] = MFMA16(pf, vf[kc][1], o[i][1]);
    }
  }

  unsigned short* obase = AOUT + rowbase;
#pragma unroll
  for (int i = 0; i < 4; ++i)
#pragma unroll
    for (int r = 0; r < 4; ++r) {
      const int q = i * 16 + hi * 4 + r;
      if (q < 49) {
        const float ri = rinv[i][r];
        obase[q * 32 + li] = f2bf(o[i][0][r] * ri);
        obase[q * 32 + 16 + li] = f2bf(o[i][1][r] * ri);
      }
    }
}

// ---------------------------------------------------------------------------
// GEMM3: out = attn @ out_w.T + out_b; A via global_load_lds with
// inverse-swizzled per-lane source (roll(+3) gather); B from W3.
// ---------------------------------------------------------------------------
__global__ __launch_bounds__(256, 2)
void k_gemm_out(const unsigned short* __restrict__ A, const unsigned short* __restrict__ W3,
                const float* __restrict__ B, float* __restrict__ OUT) {
  __shared__ unsigned short Alds[128 * 128];
  __shared__ unsigned short Blds[128 * 128];
  const int tid = threadIdx.x;
  const int bm = blockIdx.x;
  const int lane = tid & 63, wid = tid >> 6;

  {
    const char* gb = (const char*)W3 + (wid << 13) + (lane << 4);
    char* lb = (char*)Blds + (wid << 13);
#pragma unroll
    for (int r = 0; r < 8; ++r) gload_lds16(gb + (r << 10), lb + (r << 10));
  }
  {
#pragma unroll
    for (int r = 0; r < 8; ++r) {
      const int off = (wid << 13) + (r << 10) + (lane << 4);   // linear LDS byte
      const int rr = off >> 8;
      const int colb = off & 255;
      const int scol = colb ^ ((rr & 7) << 4);                 // inverse swizzle on source
      const int row = bm * 128 + rr;
      const int n = row / 3136;
      const int p = row - n * 3136;
      const int rf = p / 56, cf = p - rf * 56;
      int rs = rf + 53; if (rs >= 56) rs -= 56;                // roll(+3)
      int cs = cf + 53; if (cs >= 56) cs -= 56;
      const char* ga = (const char*)A + (((size_t)(n * 12544 + (rs * 56 + cs) * 4)) << 6) + scol;
      gload_lds16(ga, (char*)Alds + (wid << 13) + (r << 10));
    }
  }
  __syncthreads();

  const int li = lane & 15, hi = lane >> 4;
  const int rw = (wid >> 1) << 6, cw = (wid & 1) << 6;

  f32x4 acc[4][4];
#pragma unroll
  for (int i = 0; i < 4; ++i)
#pragma unroll
    for (int j = 0; j < 4; ++j) acc[i][j] = (f32x4){0.f, 0.f, 0.f, 0.f};

#pragma unroll
  for (int kc = 0; kc < 4; ++kc) {
    s16x8 af[4], bfr[4];
#pragma unroll
    for (int i = 0; i < 4; ++i) {
      const int ra = rw + i * 16 + li;
      af[i] = *(const s16x8*)((const char*)Alds + ra * 256 + ((kc * 64 + hi * 16) ^ ((ra & 7) << 4)));
      const int cb = cw + i * 16 + li;
      bfr[i] = *(const s16x8*)((const char*)Blds + cb * 256 + ((kc * 64 + hi * 16) ^ ((cb & 7) << 4)));
    }
#pragma unroll
    for (int i = 0; i < 4; ++i)
#pragma unroll
      for (int j = 0; j < 4; ++j)
        acc[i][j] = MFMA16(af[i], bfr[j], acc[i][j]);
  }

  float bias4[4];
#pragma unroll
  for (int j = 0; j < 4; ++j) bias4[j] = B[cw + j * 16 + li];
#pragma unroll
  for (int i = 0; i < 4; ++i)
#pragma unroll
    for (int r = 0; r < 4; ++r) {
      const int row = bm * 128 + rw + i * 16 + hi * 4 + r;
      float* orow = OUT + (size_t)row * 128;
#pragma unroll
      for (int j = 0; j < 4; ++j)
        orow[cw + j * 16 + li] = acc[i][j][r] + bias4[j];
    }
}

extern "C" void kernel_launch(void* const* d_in, const int* in_sizes, int n_in,
                              void* d_out, int out_size, void* d_ws, size_t ws_size,
                              hipStream_t stream) {
  const float* x = (const float*)d_in[0];
  const float* qkv_w = (const float*)d_in[1];
  const float* qkv_b = (const float*)d_in[2];
  const float* out_w = (const float*)d_in[3];
  const float* out_b = (const float*)d_in[4];
  const float* rpe = (const float*)d_in[5];
  float* out = (float*)d_out;

  unsigned short* qkv_ws = (unsigned short*)d_ws;          // 3 planes
  unsigned short* aout = qkv_ws + 3 * PLANE;               // 1 plane
  unsigned short* W2 = aout + PLANE;                       // 3*16384 bf16
  unsigned short* W3 = W2 + 3 * 16384;                     // 16384 bf16
  float* BIAS = (float*)(W3 + 16384);                      // 4*4096 f32

  k_prep<<<36, 256, 0, stream>>>(qkv_w, out_w, rpe, W2, W3, BIAS);
  k_gemm_qkv<<<784, 256, 0, stream>>>(x, W2, qkv_b, qkv_ws);
  k_attn<<<8192, 64, 0, stream>>>(qkv_ws, BIAS, aout);
  k_gemm_out<<<784, 256, 0, stream>>>(aout, W3, out_b, out);
}